// Round 8
// baseline (485.013 us; speedup 1.0000x reference)
//
#include <hip/hip_runtime.h>
#include <hip/hip_bf16.h>

// ---------------- problem constants ----------------
#define Bb   2
#define Cc   256
#define Nn   1024
#define Mm   65536
#define MCn  32           // m-chunks; reduction via f32 atomics
#define VROWS 272         // 256 desc + 3 coords + 1 weight + ones + 11 pad
#define MSTEP 32
#define MCHUNK (Mm / MCn)           // 2048
#define NIT  (MCHUNK / MSTEP)       // 64 K-steps per block

// workspace byte offsets
#define SCL_OFF  0L                               // B*M f32           (0.5 MB)
#define TMC_OFF  524288L                          // B*M*C bf16        (67 MB)   K: [b][m][c]
#define TCM_OFF  67633152L                        // B*272*M bf16      (71.3 MB) V: [b][row][m]
#define SNC_OFF  138936320L                       // B*N*C bf16        (1 MB)    Q^T: [b][n][c]
#define PARTF_OFF 139984896L                      // B*N*272 f32       (2.23 MB) atomic accum
#define PPM_OFF   142213120L                      // B*N u32           (8 KB)    atomic max p
#define PS_OFF    142221312L                      // [B][4][M] f32 sums   (2 MB)
#define PS2_OFF   144318464L                      // [B][4][M] f32 sumsq  (2 MB) end 146.4MB
#define ZERO_BYTES 2236416L                       // PARTF + PPM contiguous

// output float offsets
#define O_COORD 0L
#define O_W     6144L
#define O_DESC  8192L
#define O_P2D   532480L
#define O_VALID 536576L
#define O_MAXSM 538624L

using f32x4 = __attribute__((ext_vector_type(4))) float;
using s16x8 = __attribute__((ext_vector_type(8))) short;

__device__ inline unsigned short f2bf(float x) {
    union { float f; unsigned int u; } v; v.f = x;
    unsigned int r = v.u + 0x7FFFu + ((v.u >> 16) & 1u);   // RNE
    return (unsigned short)(r >> 16);
}
__device__ inline float exp2v(float x) {
    float r; asm("v_exp_f32 %0, %1" : "=v"(r) : "v"(x)); return r;
}
__device__ inline unsigned int cvtpk(float lo, float hi) {
    unsigned int r;
    asm("v_cvt_pk_bf16_f32 %0, %1, %2" : "=v"(r) : "v"(lo), "v"(hi));
    return r;
}

__device__ inline void gld_lds16(const unsigned short* g, unsigned short* l) {
    __builtin_amdgcn_global_load_lds(
        (const __attribute__((address_space(1))) unsigned int*)g,
        (__attribute__((address_space(3))) unsigned int*)l, 16, 0, 0);
}

// ------- prep A: tgt_desc f32 -> tmc bf16 [b][m][c] + tcm bf16 [b][c][m],
//                 plus per-(c-block, m) partial sums for the column stats -------
__global__ void k_prep_tgt(const float* __restrict__ tgt,
                           unsigned short* __restrict__ tmc,
                           unsigned short* __restrict__ tcm,
                           float* __restrict__ ps,
                           float* __restrict__ ps2) {
    __shared__ float lds[64][65];
    __shared__ float sm[4][64], sm2[4][64];
    int b = blockIdx.z, cy = blockIdx.y, c0 = cy * 64;
    long m0 = (long)blockIdx.x * 64;
    int ty = threadIdx.x >> 6, tx = threadIdx.x & 63;
    float s = 0.f, s2 = 0.f;
    #pragma unroll
    for (int k = 0; k < 16; ++k) {
        int ci = 4 * k + ty;
        float v = tgt[((long)b * Cc + c0 + ci) * Mm + m0 + tx];
        lds[ci][tx] = v;
        s += v; s2 += v * v;
        tcm[((long)b * VROWS + c0 + ci) * Mm + m0 + tx] = f2bf(v);
    }
    sm[ty][tx] = s; sm2[ty][tx] = s2;
    __syncthreads();
    #pragma unroll
    for (int k = 0; k < 16; ++k) {
        int mi = 4 * k + ty;
        tmc[((long)b * Mm + m0 + mi) * Cc + c0 + tx] = f2bf(lds[tx][mi]);
    }
    if (ty == 0) {
        long o = ((long)b * 4 + cy) * Mm + m0 + tx;
        ps[o]  = (sm[0][tx] + sm[1][tx]) + (sm[2][tx] + sm[3][tx]);
        ps2[o] = (sm2[0][tx] + sm2[1][tx]) + (sm2[2][tx] + sm2[3][tx]);
    }
}

// ------- prep B: finish stats -> scl; write coords/weights/ones rows of V -------
__global__ void k_stats(const float* __restrict__ ps,
                        const float* __restrict__ ps2,
                        const float* __restrict__ coords,
                        const float* __restrict__ weights,
                        float* __restrict__ scl,
                        unsigned short* __restrict__ tcm) {
    int b = blockIdx.y;
    long m = (long)blockIdx.x * 256 + threadIdx.x;
    float s = 0.f, s2 = 0.f;
    #pragma unroll
    for (int k = 0; k < 4; ++k) {
        long o = ((long)b * 4 + k) * Mm + m;
        s += ps[o]; s2 += ps2[o];
    }
    float var = fmaxf((s2 - s * s * (1.0f / Cc)) * (1.0f / (Cc - 1)), 1e-20f);
    scl[(long)b * Mm + m] = 1.4426950408889634f * rsqrtf(var) * (1.0f / (Cc * 0.01f));
    unsigned short* vrow = tcm + ((long)b * VROWS + 256) * Mm + m;
    #pragma unroll
    for (int i = 0; i < 3; ++i) vrow[(long)i * Mm] = f2bf(coords[((long)b * 3 + i) * Mm + m]);
    vrow[3L * Mm] = f2bf(weights[(long)b * Mm + m]);
    vrow[4L * Mm] = 0x3F80;   // ones row (channel 260): Z comes out of the PV MFMA
    #pragma unroll
    for (int i = 5; i < 16; ++i) vrow[(long)i * Mm] = 0;
}

// ------- prep C: src_desc_norm f32 -> snc bf16 [b][n][c] -------
__global__ void k_prep_src(const float* __restrict__ src, unsigned short* __restrict__ snc) {
    __shared__ float lds[64][65];
    int b = blockIdx.z, c0 = blockIdx.y * 64, n0 = blockIdx.x * 64;
    int ty = threadIdx.x >> 6, tx = threadIdx.x & 63;
    #pragma unroll
    for (int k = 0; k < 16; ++k)
        lds[4 * k + ty][tx] = src[((long)b * Cc + c0 + 4 * k + ty) * Nn + n0 + tx];
    __syncthreads();
    #pragma unroll
    for (int k = 0; k < 16; ++k) {
        int ni = 4 * k + ty;
        snc[((long)b * Nn + n0 + ni) * Cc + c0 + tx] = f2bf(lds[tx][ni]);
    }
}

// ------- main fused kernel: 8 waves, phase-staggered wave groups -------
// Waves 0-3: QK(s) then PV(s).  Waves 4-7: PV(s-1) then QK(s).
// Each SIMD hosts one wave of each group -> complementary phases cover each
// other's stalls. K double-buffered, V triple-buffered, group-B pbuf dbuf'd.
__global__ __launch_bounds__(512, 2) void k_main(const unsigned short* __restrict__ tmc,
                                                 const unsigned short* __restrict__ tcm,
                                                 const unsigned short* __restrict__ snc,
                                                 const float* __restrict__ scl,
                                                 float* __restrict__ partf,
                                                 unsigned int* __restrict__ ppmax) {
    __shared__ __align__(16) unsigned short kb[2][8192];            // 32 KB
    __shared__ __align__(16) unsigned short vb[3][8704];            // 52.2 KB
    __shared__ __align__(16) unsigned short pbA[4][2][16][40];      // 10.2 KB
    __shared__ __align__(16) unsigned short pbB[2][4][2][16][40];   // 20.5 KB

    int w = threadIdx.x >> 6, lane = threadIdx.x & 63;
    int l15 = lane & 15, lg = lane >> 4;
    int b = blockIdx.z, nt = blockIdx.y, mc = blockIdx.x;
    int nb = nt * 256 + w * 32;
    long mbase = (long)mc * MCHUNK;

    // Q^T B-fragments for 2 n-subtiles
    s16x8 qf[2][8];
    #pragma unroll
    for (int st = 0; st < 2; ++st) {
        const unsigned short* qp = snc + ((long)b * Nn + nb + st * 16 + l15) * Cc + lg * 8;
        #pragma unroll
        for (int cc = 0; cc < 8; ++cc) qf[st][cc] = *(const s16x8*)(qp + cc * 32);
    }

    f32x4 acc[2][17];
    #pragma unroll
    for (int st = 0; st < 2; ++st)
        #pragma unroll
        for (int t = 0; t < 17; ++t) acc[st][t] = (f32x4){0.f, 0.f, 0.f, 0.f};
    float pmax[2] = {0.f, 0.f};

    // ---- staging source pointers (per-lane, pre-swizzled) ----
    const unsigned short* tmcb = tmc + (long)b * Mm * Cc;
    const unsigned short* tcmb = tcm + (long)b * VROWS * (long)Mm;
    const unsigned short* ksrc[2];
    #pragma unroll
    for (int i = 0; i < 2; ++i) {
        int ins = 2 * w + i;                 // K instr 0..15, covers rows 2*ins, 2*ins+1
        int row = 2 * ins + (lane >> 5);
        int gs  = (lane & 31) ^ (row & 7);   // pre-swizzled 16B slot
        ksrc[i] = tmcb + (mbase + row) * Cc + gs * 8;
    }
    const unsigned short* vsrc[3];
    int vj = ((lane & 3) ^ ((lane >> 3) & 3)) * 8;   // chunk-XOR pre-swizzle
    #pragma unroll
    for (int i = 0; i < 3; ++i) {
        int ins = (i < 2) ? (2 * w + i) : 16;  // V instr 0..16, covers 16 rows
        int row = ins * 16 + (lane >> 2);
        vsrc[i] = tcmb + (long)row * Mm + mbase + vj;
    }

    const float* sclb = scl + (long)b * Mm;

    auto stage = [&](unsigned short* kd, unsigned short* vd) {
        #pragma unroll
        for (int i = 0; i < 2; ++i) gld_lds16(ksrc[i], kd + (2 * w + i) * 512);
        #pragma unroll
        for (int i = 0; i < 2; ++i) gld_lds16(vsrc[i], vd + (2 * w + i) * 512);
        if (w == 7) gld_lds16(vsrc[2], vd + 16 * 512);
    };
    auto advance = [&]() {
        #pragma unroll
        for (int i = 0; i < 2; ++i) ksrc[i] += MSTEP * Cc;
        #pragma unroll
        for (int i = 0; i < 3; ++i) vsrc[i] += MSTEP;
    };

    int ksw = (l15 & 7) << 3;              // K read swizzle (elements)
    int vsw = (lg ^ ((l15 >> 1) & 3)) * 8; // V read chunk swizzle (elements)

    // QK(s): K tile -> exp -> packed P into pw
    auto qk_step = [&](const unsigned short* kbc, long m0, unsigned short* pw) {
        #pragma unroll
        for (int t = 0; t < 2; ++t) {
            f32x4 dA = (f32x4){0.f, 0.f, 0.f, 0.f};
            f32x4 dB = (f32x4){0.f, 0.f, 0.f, 0.f};
            const unsigned short* kr = kbc + (t * 16 + l15) * Cc;
            #pragma unroll
            for (int cc = 0; cc < 8; ++cc) {
                s16x8 kf = *(const s16x8*)(kr + ((cc * 32 + lg * 8) ^ ksw));
                dA = __builtin_amdgcn_mfma_f32_16x16x32_bf16(kf, qf[0][cc], dA, 0, 0, 0);
                dB = __builtin_amdgcn_mfma_f32_16x16x32_bf16(kf, qf[1][cc], dB, 0, 0, 0);
            }
            float4 sc = *(const float4*)(sclb + m0 + t * 16 + lg * 4);
            #pragma unroll
            for (int st = 0; st < 2; ++st) {
                f32x4 d = st ? dB : dA;
                float p0 = exp2v(d.x * sc.x);
                float p1 = exp2v(d.y * sc.y);
                float p2 = exp2v(d.z * sc.z);
                float p3 = exp2v(d.w * sc.w);
                pmax[st] = fmaxf(pmax[st], fmaxf(fmaxf(p0, p1), fmaxf(p2, p3)));
                unsigned long long pk =
                    (unsigned long long)cvtpk(p0, p1) | ((unsigned long long)cvtpk(p2, p3) << 32);
                *(unsigned long long*)(pw + (st * 16 + l15) * 40 + t * 16 + lg * 4) = pk;
            }
        }
    };
    // PV: V tile x packed P -> acc
    auto pv_step = [&](const unsigned short* vbc, const unsigned short* pr) {
        s16x8 pfA = *(const s16x8*)(pr + l15 * 40 + lg * 8);
        s16x8 pfB = *(const s16x8*)(pr + (16 + l15) * 40 + lg * 8);
        #pragma unroll
        for (int t = 0; t < 17; ++t) {
            s16x8 vf = *(const s16x8*)(vbc + (t * 16 + l15) * MSTEP + vsw);
            acc[0][t] = __builtin_amdgcn_mfma_f32_16x16x32_bf16(vf, pfA, acc[0][t], 0, 0, 0);
            acc[1][t] = __builtin_amdgcn_mfma_f32_16x16x32_bf16(vf, pfB, acc[1][t], 0, 0, 0);
        }
    };

    stage(kb[0], vb[0]);
    advance();
    __syncthreads();

    if (w < 4) {
        // group A: QK(s) ; PV(s)
        unsigned short* pme = &pbA[w][0][0][0];
        for (int s = 0; s < NIT; ++s) {
            if (s + 1 < NIT) { stage(kb[(s + 1) & 1], vb[(s + 1) % 3]); advance(); }
            qk_step(kb[s & 1], mbase + (long)s * MSTEP, pme);
            pv_step(vb[s % 3], pme);
            __syncthreads();
        }
    } else {
        // group B: PV(s-1) ; QK(s)   (one-step software pipeline)
        int wb = w - 4;
        for (int s = 0; s < NIT; ++s) {
            if (s + 1 < NIT) { stage(kb[(s + 1) & 1], vb[(s + 1) % 3]); advance(); }
            if (s) pv_step(vb[(s - 1) % 3], &pbB[(s - 1) & 1][wb][0][0][0]);
            qk_step(kb[s & 1], mbase + (long)s * MSTEP, &pbB[s & 1][wb][0][0][0]);
            __syncthreads();
        }
        pv_step(vb[(NIT - 1) % 3], &pbB[(NIT - 1) & 1][wb][0][0][0]);
    }

    // reduce pmax across lane-groups; atomic-accumulate partials (f32)
    #pragma unroll
    for (int st = 0; st < 2; ++st) {
        float pt = fmaxf(pmax[st], __shfl_xor(pmax[st], 16));
        pt = fmaxf(pt, __shfl_xor(pt, 32));
        if (lane < 16)
            atomicMax(ppmax + (long)b * Nn + nb + st * 16 + lane, __float_as_uint(pt));
        float* po = partf + ((long)b * Nn + nb + st * 16 + l15) * VROWS;
        #pragma unroll
        for (int t = 0; t < 17; ++t) {
            f32x4 a = acc[st][t];
            atomicAdd(&po[t * 16 + lg * 4 + 0], a.x);
            atomicAdd(&po[t * 16 + lg * 4 + 1], a.y);
            atomicAdd(&po[t * 16 + lg * 4 + 2], a.z);
            atomicAdd(&po[t * 16 + lg * 4 + 3], a.w);
        }
    }
}

// ------- epilogue: normalize, zn(descs), 2D projection, max_softmax -------
__global__ void k_epi(const float* __restrict__ partf,
                      const unsigned int* __restrict__ ppmax,
                      float* __restrict__ out) {
    int w = threadIdx.x >> 6, lane = threadIdx.x & 63;
    int bn = blockIdx.x * 4 + w;
    int b = bn >> 10, n = bn & 1023;

    const float* pr = partf + (long)bn * VROWS;
    float Z = pr[260];
    float invZ = 1.0f / Z;

    float dv[4], s1 = 0.f, s2 = 0.f;
    #pragma unroll
    for (int k = 0; k < 4; ++k) {
        float d = pr[lane + 64 * k] * invZ;
        dv[k] = d; s1 += d; s2 += d * d;
    }
    #pragma unroll
    for (int off = 1; off < 64; off <<= 1) { s1 += __shfl_xor(s1, off); s2 += __shfl_xor(s2, off); }
    float mean = s1 * (1.0f / 256.0f);
    float var = fmaxf((s2 - 256.0f * mean * mean) * (1.0f / 255.0f), 1e-20f);
    float istd = 1.0f / sqrtf(var);
    #pragma unroll
    for (int k = 0; k < 4; ++k)
        out[O_DESC + ((long)b * Cc + lane + 64 * k) * Nn + n] = (dv[k] - mean) * istd;

    if (lane == 0) {
        float pc0 = pr[256] * invZ, pc1 = pr[257] * invZ, pc2 = pr[258] * invZ;
        float wv = pr[259] * invZ;
        out[O_COORD + ((long)b * 3 + 0) * Nn + n] = pc0;
        out[O_COORD + ((long)b * 3 + 1) * Nn + n] = pc1;
        out[O_COORD + ((long)b * 3 + 2) * Nn + n] = pc2;
        out[O_W + (long)b * Nn + n] = wv;
        const float cmin = 33.048f;                 // (256/2 - 0.5) * 0.2592
        out[O_P2D + ((long)b * Nn + n) * 2 + 0] = (cmin + pc1) * (1.0f / 0.2592f);
        out[O_P2D + ((long)b * Nn + n) * 2 + 1] = (cmin - pc0) * (1.0f / 0.2592f);
        out[O_VALID + (long)b * Nn + n] = 1.0f;
        float pm = __uint_as_float(ppmax[bn]) * invZ;
        atomicMax((unsigned int*)out + O_MAXSM + b, __float_as_uint(pm));
    }
}

extern "C" void kernel_launch(void* const* d_in, const int* in_sizes, int n_in,
                              void* d_out, int out_size, void* d_ws, size_t ws_size,
                              hipStream_t stream) {
    const float* tgt_coords  = (const float*)d_in[1];
    const float* tgt_weights = (const float*)d_in[3];
    const float* src_desc    = (const float*)d_in[5];
    const float* tgt_desc    = (const float*)d_in[6];

    char* ws = (char*)d_ws;
    float* scl           = (float*)(ws + SCL_OFF);
    unsigned short* tmc  = (unsigned short*)(ws + TMC_OFF);
    unsigned short* tcm  = (unsigned short*)(ws + TCM_OFF);
    unsigned short* snc  = (unsigned short*)(ws + SNC_OFF);
    float* partf         = (float*)(ws + PARTF_OFF);
    unsigned int* ppmax  = (unsigned int*)(ws + PPM_OFF);
    float* ps            = (float*)(ws + PS_OFF);
    float* ps2           = (float*)(ws + PS2_OFF);
    float* out           = (float*)d_out;

    k_prep_tgt<<<dim3(Mm / 64, Cc / 64, Bb), 256, 0, stream>>>(tgt_desc, tmc, tcm, ps, ps2);
    k_stats<<<dim3(Mm / 256, Bb), 256, 0, stream>>>(ps, ps2, tgt_coords, tgt_weights, scl, tcm);
    k_prep_src<<<dim3(Nn / 64, Cc / 64, Bb), 256, 0, stream>>>(src_desc, snc);
    hipMemsetAsync(ws + PARTF_OFF, 0, ZERO_BYTES, stream);
    hipMemsetAsync((char*)d_out + O_MAXSM * 4, 0, 2 * sizeof(float), stream);
    k_main<<<dim3(MCn, Nn / 256, Bb), 512, 0, stream>>>(tmc, tcm, snc, scl, partf, ppmax);
    k_epi<<<dim3((Bb * Nn) / 4), 256, 0, stream>>>(partf, ppmax, out);
}

// Round 10
// 428.135 us; speedup vs baseline: 1.1329x; 1.1329x over previous
//
#include <hip/hip_runtime.h>
#include <hip/hip_bf16.h>

// ---------------- problem constants ----------------
#define Bb   2
#define Cc   256
#define Nn   1024
#define Mm   65536
#define MCn  16           // m-chunks (global partials, bf16)
#define VROWS 272         // 256 desc + 3 coords + 1 weight + ones + 11 pad
#define MSTEP 32
#define MCHUNK (Mm / MCn)           // 4096
#define NIT  (MCHUNK / MSTEP)       // 128 K-steps per block

// workspace byte offsets
#define SCL_OFF  0L                               // B*M f32           (0.5 MB)
#define TMC_OFF  524288L                          // B*M*C bf16        (67 MB)   K: [b][m][c]
#define TCM_OFF  67633152L                        // B*272*M bf16      (71.3 MB) V: [b][row][m]
#define SNC_OFF  138936320L                       // B*N*C bf16        (1 MB)    Q^T: [b][n][c]
#define PART_OFF 139984896L                       // B*16*N*272 bf16   (17.8 MB)
#define ZP_OFF   157810688L                       // B*16*N f32
#define PP_OFF   157941760L                       // B*16*N f32  (end 158072832)
// stats partials live in the part region (used before k_main writes part)
#define PS_OFF   PART_OFF                         // [B][4][M] f32 sums   (2 MB)
#define PS2_OFF  (PART_OFF + 2097152L)            // [B][4][M] f32 sumsq  (2 MB)

// output float offsets
#define O_COORD 0L
#define O_W     6144L
#define O_DESC  8192L
#define O_P2D   532480L
#define O_VALID 536576L
#define O_MAXSM 538624L

using f32x4 = __attribute__((ext_vector_type(4))) float;
using s16x8 = __attribute__((ext_vector_type(8))) short;

__device__ inline unsigned short f2bf(float x) {
    union { float f; unsigned int u; } v; v.f = x;
    unsigned int r = v.u + 0x7FFFu + ((v.u >> 16) & 1u);   // RNE
    return (unsigned short)(r >> 16);
}
__device__ inline float bf2f(unsigned short u) {
    union { unsigned int u; float f; } v; v.u = ((unsigned int)u) << 16;
    return v.f;
}
__device__ inline float exp2v(float x) {
    float r; asm("v_exp_f32 %0, %1" : "=v"(r) : "v"(x)); return r;
}
__device__ inline unsigned int cvtpk(float lo, float hi) {
    unsigned int r;
    asm("v_cvt_pk_bf16_f32 %0, %1, %2" : "=v"(r) : "v"(lo), "v"(hi));
    return r;
}

__device__ inline void gld_lds16(const unsigned short* g, unsigned short* l) {
    __builtin_amdgcn_global_load_lds(
        (const __attribute__((address_space(1))) unsigned int*)g,
        (__attribute__((address_space(3))) unsigned int*)l, 16, 0, 0);
}

// ------- prep A: tgt_desc f32 -> tmc bf16 [b][m][c] + tcm bf16 [b][c][m],
//                 plus per-(c-block, m) partial sums for the column stats -------
__global__ void k_prep_tgt(const float* __restrict__ tgt,
                           unsigned short* __restrict__ tmc,
                           unsigned short* __restrict__ tcm,
                           float* __restrict__ ps,
                           float* __restrict__ ps2) {
    __shared__ float lds[64][65];
    __shared__ float sm[4][64], sm2[4][64];
    int b = blockIdx.z, cy = blockIdx.y, c0 = cy * 64;
    long m0 = (long)blockIdx.x * 64;
    int ty = threadIdx.x >> 6, tx = threadIdx.x & 63;
    float s = 0.f, s2 = 0.f;
    #pragma unroll
    for (int k = 0; k < 16; ++k) {
        int ci = 4 * k + ty;
        float v = tgt[((long)b * Cc + c0 + ci) * Mm + m0 + tx];
        lds[ci][tx] = v;
        s += v; s2 += v * v;
        tcm[((long)b * VROWS + c0 + ci) * Mm + m0 + tx] = f2bf(v);
    }
    sm[ty][tx] = s; sm2[ty][tx] = s2;
    __syncthreads();
    #pragma unroll
    for (int k = 0; k < 16; ++k) {
        int mi = 4 * k + ty;
        tmc[((long)b * Mm + m0 + mi) * Cc + c0 + tx] = f2bf(lds[tx][mi]);
    }
    if (ty == 0) {
        long o = ((long)b * 4 + cy) * Mm + m0 + tx;
        ps[o]  = (sm[0][tx] + sm[1][tx]) + (sm[2][tx] + sm[3][tx]);
        ps2[o] = (sm2[0][tx] + sm2[1][tx]) + (sm2[2][tx] + sm2[3][tx]);
    }
}

// ------- prep B: finish stats -> scl; write coords/weights/ones rows of V -------
__global__ void k_stats(const float* __restrict__ ps,
                        const float* __restrict__ ps2,
                        const float* __restrict__ coords,
                        const float* __restrict__ weights,
                        float* __restrict__ scl,
                        unsigned short* __restrict__ tcm) {
    int b = blockIdx.y;
    long m = (long)blockIdx.x * 256 + threadIdx.x;
    float s = 0.f, s2 = 0.f;
    #pragma unroll
    for (int k = 0; k < 4; ++k) {
        long o = ((long)b * 4 + k) * Mm + m;
        s += ps[o]; s2 += ps2[o];
    }
    float var = fmaxf((s2 - s * s * (1.0f / Cc)) * (1.0f / (Cc - 1)), 1e-20f);
    scl[(long)b * Mm + m] = 1.4426950408889634f * rsqrtf(var) * (1.0f / (Cc * 0.01f));
    unsigned short* vrow = tcm + ((long)b * VROWS + 256) * Mm + m;
    #pragma unroll
    for (int i = 0; i < 3; ++i) vrow[(long)i * Mm] = f2bf(coords[((long)b * 3 + i) * Mm + m]);
    vrow[3L * Mm] = f2bf(weights[(long)b * Mm + m]);
    vrow[4L * Mm] = 0x3F80;   // ones row (channel 260): Z comes out of the PV MFMA
    #pragma unroll
    for (int i = 5; i < 16; ++i) vrow[(long)i * Mm] = 0;
}

// ------- prep C: src_desc_norm f32 -> snc bf16 [b][n][c] -------
__global__ void k_prep_src(const float* __restrict__ src, unsigned short* __restrict__ snc) {
    __shared__ float lds[64][65];
    int b = blockIdx.z, c0 = blockIdx.y * 64, n0 = blockIdx.x * 64;
    int ty = threadIdx.x >> 6, tx = threadIdx.x & 63;
    #pragma unroll
    for (int k = 0; k < 16; ++k)
        lds[4 * k + ty][tx] = src[((long)b * Cc + c0 + 4 * k + ty) * Nn + n0 + tx];
    __syncthreads();
    #pragma unroll
    for (int k = 0; k < 16; ++k) {
        int ni = 4 * k + ty;
        snc[((long)b * Nn + n0 + ni) * Cc + c0 + tx] = f2bf(lds[tx][ni]);
    }
}

// ------- main fused kernel: K streamed global->registers, V LDS-staged -------
// 4 waves * 32 n = 128 n per block; 128 steps of 32 m. Q resident in regs,
// K-fragments double-banked in regs (loaded 1 iter ahead, L3-resident source),
// V triple-buffered in LDS, P via double-buffered LDS roundtrip, PV runs one
// step behind QK so its independent MFMAs fill QK's dependency bubbles.
__global__ __launch_bounds__(256, 1) void k_main(const unsigned short* __restrict__ tmc,
                                                 const unsigned short* __restrict__ tcm,
                                                 const unsigned short* __restrict__ snc,
                                                 const float* __restrict__ scl,
                                                 unsigned short* __restrict__ part,
                                                 float* __restrict__ zp,
                                                 float* __restrict__ pp) {
    __shared__ __align__(16) unsigned short vb[3][8704];              // 17 KB x3
    __shared__ __align__(16) unsigned short pbuf[2][4][2][16][40];    // 20.5 KB

    int w = threadIdx.x >> 6, lane = threadIdx.x & 63;
    int l15 = lane & 15, lg = lane >> 4;
    int b = blockIdx.z, nt = blockIdx.y, mc = blockIdx.x;
    int nb = nt * 128 + w * 32;
    long mbase = (long)mc * MCHUNK;

    // Q^T B-fragments for 2 n-subtiles (permanent registers)
    s16x8 qf[2][8];
    #pragma unroll
    for (int st = 0; st < 2; ++st) {
        const unsigned short* qp = snc + ((long)b * Nn + nb + st * 16 + l15) * Cc + lg * 8;
        #pragma unroll
        for (int cc = 0; cc < 8; ++cc) qf[st][cc] = *(const s16x8*)(qp + cc * 32);
    }

    f32x4 acc[2][17];
    #pragma unroll
    for (int st = 0; st < 2; ++st)
        #pragma unroll
        for (int t = 0; t < 17; ++t) acc[st][t] = (f32x4){0.f, 0.f, 0.f, 0.f};
    float pmax[2] = {0.f, 0.f};

    // ---- K global stream pointers (per-lane, registers, no LDS) ----
    const unsigned short* tmcb = tmc + (long)b * Mm * Cc;
    const unsigned short* kt0 = tmcb + (mbase + l15) * Cc + lg * 8;        // t=0 rows
    const unsigned short* kt1 = tmcb + (mbase + 16 + l15) * Cc + lg * 8;   // t=1 rows

    // ---- V staging pointers (per-lane, chunk-XOR pre-swizzled) ----
    const unsigned short* tcmb = tcm + (long)b * VROWS * (long)Mm;
    const unsigned short* vsrc[5];
    int vj = ((lane & 3) ^ ((lane >> 3) & 3)) * 8;
    #pragma unroll
    for (int i = 0; i < 5; ++i) {
        int ins = (i < 4) ? (w * 4 + i) : 16;
        int row = ins * 16 + (lane >> 2);
        vsrc[i] = tcmb + (long)row * Mm + mbase + vj;
    }

    const float* sclb = scl + (long)b * Mm;

    auto stagev = [&](unsigned short* vd) {
        #pragma unroll
        for (int i = 0; i < 4; ++i) gld_lds16(vsrc[i], vd + (w * 4 + i) * 512);
        if (w == 3) gld_lds16(vsrc[4], vd + 16 * 512);
        #pragma unroll
        for (int i = 0; i < 5; ++i) vsrc[i] += MSTEP;
    };
    auto load_k = [&](s16x8* d0, s16x8* d1) {
        #pragma unroll
        for (int cc = 0; cc < 8; ++cc) {
            d0[cc] = *(const s16x8*)(kt0 + cc * 32);
            d1[cc] = *(const s16x8*)(kt1 + cc * 32);
        }
        kt0 += MSTEP * Cc;
        kt1 += MSTEP * Cc;
    };

    int vsw = (lg ^ ((l15 >> 1) & 3)) * 8;   // V read chunk swizzle (elements)

    float4 scA, scB;

    // QK half-tile: K-frags from registers -> exp -> packed P rows t*16..
    auto qk_half = [&](const s16x8* kf, int t, float4 sc, unsigned short* pw) {
        f32x4 dA = (f32x4){0.f, 0.f, 0.f, 0.f};
        f32x4 dB = (f32x4){0.f, 0.f, 0.f, 0.f};
        #pragma unroll
        for (int cc = 0; cc < 8; ++cc) {
            dA = __builtin_amdgcn_mfma_f32_16x16x32_bf16(kf[cc], qf[0][cc], dA, 0, 0, 0);
            dB = __builtin_amdgcn_mfma_f32_16x16x32_bf16(kf[cc], qf[1][cc], dB, 0, 0, 0);
        }
        #pragma unroll
        for (int st = 0; st < 2; ++st) {
            f32x4 d = st ? dB : dA;
            float p0 = exp2v(d.x * sc.x);
            float p1 = exp2v(d.y * sc.y);
            float p2 = exp2v(d.z * sc.z);
            float p3 = exp2v(d.w * sc.w);
            pmax[st] = fmaxf(pmax[st], fmaxf(fmaxf(p0, p1), fmaxf(p2, p3)));
            unsigned long long pk =
                (unsigned long long)cvtpk(p0, p1) | ((unsigned long long)cvtpk(p2, p3) << 32);
            *(unsigned long long*)(pw + (st * 16 + l15) * 40 + t * 16 + lg * 4) = pk;
        }
    };
    auto pv_step = [&](const unsigned short* vbc, const unsigned short* pr) {
        s16x8 pfA = *(const s16x8*)(pr + l15 * 40 + lg * 8);
        s16x8 pfB = *(const s16x8*)(pr + (16 + l15) * 40 + lg * 8);
        #pragma unroll
        for (int t = 0; t < 17; ++t) {
            s16x8 vf = *(const s16x8*)(vbc + (t * 16 + l15) * MSTEP + vsw);
            acc[0][t] = __builtin_amdgcn_mfma_f32_16x16x32_bf16(vf, pfA, acc[0][t], 0, 0, 0);
            acc[1][t] = __builtin_amdgcn_mfma_f32_16x16x32_bf16(vf, pfB, acc[1][t], 0, 0, 0);
        }
    };

    s16x8 kA0[8], kA1[8], kB0[8], kB1[8];

    // prologue: V(0) -> vb[0], K(0) -> bank A
    stagev(vb[0]);
    load_k(kA0, kA1);
    scA = *(const float4*)(sclb + mbase + lg * 4);
    scB = *(const float4*)(sclb + mbase + 16 + lg * 4);
    __syncthreads();

    auto body = [&](int s, const s16x8* kc0, const s16x8* kc1, s16x8* kn0, s16x8* kn1) {
        if (s + 1 < NIT) {
            stagev(vb[(s + 1) % 3]);           // V tile s+1
            load_k(kn0, kn1);                  // K tile s+1 -> other bank
        }
        int sn = (s + 1 < NIT) ? s + 1 : s;
        float4 nA = *(const float4*)(sclb + mbase + (long)sn * MSTEP + lg * 4);
        float4 nB = *(const float4*)(sclb + mbase + (long)sn * MSTEP + 16 + lg * 4);

        unsigned short* pw = &pbuf[s & 1][w][0][0][0];
        qk_half(kc0, 0, scA, pw);
        qk_half(kc1, 1, scB, pw);

        if (s) pv_step(vb[(s + 2) % 3], &pbuf[(s & 1) ^ 1][w][0][0][0]);

        scA = nA; scB = nB;
        __syncthreads();
    };

    for (int s = 0; s < NIT; s += 2) {
        body(s,     kA0, kA1, kB0, kB1);
        body(s + 1, kB0, kB1, kA0, kA1);
    }
    // tail: PV(NIT-1)
    pv_step(vb[(NIT - 1) % 3], &pbuf[(NIT - 1) & 1][w][0][0][0]);

    // Z sits in acc[st][16].x on lanes lg==1 (channel 260 = ones row)
    #pragma unroll
    for (int st = 0; st < 2; ++st) {
        float pt = fmaxf(pmax[st], __shfl_xor(pmax[st], 16));
        pt = fmaxf(pt, __shfl_xor(pt, 32));
        long zi = ((long)(b * MCn + mc)) * Nn + nb + st * 16;
        if (lg == 1) zp[zi + l15] = acc[st][16].x;
        if (lane < 16) pp[zi + lane] = pt;
        unsigned short* po = part + (((long)(b * MCn + mc) * Nn) + nb + st * 16 + l15) * VROWS;
        #pragma unroll
        for (int t = 0; t < 17; ++t) {
            f32x4 a = acc[st][t];
            unsigned long long pk =
                (unsigned long long)cvtpk(a.x, a.y) | ((unsigned long long)cvtpk(a.z, a.w) << 32);
            *(unsigned long long*)&po[t * 16 + lg * 4] = pk;
        }
    }
}

// ------- epilogue: combine m-chunks, normalize, zn(descs), 2D projection, max_softmax -------
__global__ void k_epi(const unsigned short* __restrict__ part,
                      const float* __restrict__ zp,
                      const float* __restrict__ pp,
                      float* __restrict__ out) {
    int w = threadIdx.x >> 6, lane = threadIdx.x & 63;
    int bn = blockIdx.x * 4 + w;
    int b = bn >> 10, n = bn & 1023;

    float Z = 0.f, pm = 0.f;
    #pragma unroll
    for (int mc = 0; mc < MCn; ++mc) {
        long zi = ((long)(b * MCn + mc)) * Nn + n;
        Z += zp[zi];
        pm = fmaxf(pm, pp[zi]);
    }
    float invZ = 1.0f / Z;

    float dv[4], s1 = 0.f, s2 = 0.f;
    #pragma unroll
    for (int k = 0; k < 4; ++k) {
        int c = lane + 64 * k;
        float s = 0.f;
        #pragma unroll
        for (int mc = 0; mc < MCn; ++mc)
            s += bf2f(part[((long)(b * MCn + mc) * Nn + n) * VROWS + c]);
        float d = s * invZ;
        dv[k] = d; s1 += d; s2 += d * d;
    }
    #pragma unroll
    for (int off = 1; off < 64; off <<= 1) { s1 += __shfl_xor(s1, off); s2 += __shfl_xor(s2, off); }
    float mean = s1 * (1.0f / 256.0f);
    float var = fmaxf((s2 - 256.0f * mean * mean) * (1.0f / 255.0f), 1e-20f);
    float istd = 1.0f / sqrtf(var);
    #pragma unroll
    for (int k = 0; k < 4; ++k)
        out[O_DESC + ((long)b * Cc + lane + 64 * k) * Nn + n] = (dv[k] - mean) * istd;

    float ex = 0.f;
    if (lane < 4) {
        int c = 256 + lane;
        #pragma unroll
        for (int mc = 0; mc < MCn; ++mc)
            ex += bf2f(part[((long)(b * MCn + mc) * Nn + n) * VROWS + c]);
        ex *= invZ;
    }
    float pc0 = __shfl(ex, 0), pc1 = __shfl(ex, 1), pc2 = __shfl(ex, 2), wv = __shfl(ex, 3);
    if (lane == 0) {
        out[O_COORD + ((long)b * 3 + 0) * Nn + n] = pc0;
        out[O_COORD + ((long)b * 3 + 1) * Nn + n] = pc1;
        out[O_COORD + ((long)b * 3 + 2) * Nn + n] = pc2;
        out[O_W + (long)b * Nn + n] = wv;
        const float cmin = 33.048f;                 // (256/2 - 0.5) * 0.2592
        out[O_P2D + ((long)b * Nn + n) * 2 + 0] = (cmin + pc1) * (1.0f / 0.2592f);
        out[O_P2D + ((long)b * Nn + n) * 2 + 1] = (cmin - pc0) * (1.0f / 0.2592f);
        out[O_VALID + (long)b * Nn + n] = 1.0f;
        atomicMax((unsigned int*)out + O_MAXSM + b, __float_as_uint(pm * invZ));
    }
}

extern "C" void kernel_launch(void* const* d_in, const int* in_sizes, int n_in,
                              void* d_out, int out_size, void* d_ws, size_t ws_size,
                              hipStream_t stream) {
    const float* tgt_coords  = (const float*)d_in[1];
    const float* tgt_weights = (const float*)d_in[3];
    const float* src_desc    = (const float*)d_in[5];
    const float* tgt_desc    = (const float*)d_in[6];

    char* ws = (char*)d_ws;
    float* scl           = (float*)(ws + SCL_OFF);
    unsigned short* tmc  = (unsigned short*)(ws + TMC_OFF);
    unsigned short* tcm  = (unsigned short*)(ws + TCM_OFF);
    unsigned short* snc  = (unsigned short*)(ws + SNC_OFF);
    unsigned short* part = (unsigned short*)(ws + PART_OFF);
    float* ps            = (float*)(ws + PS_OFF);
    float* ps2           = (float*)(ws + PS2_OFF);
    float* zp            = (float*)(ws + ZP_OFF);
    float* pp            = (float*)(ws + PP_OFF);
    float* out           = (float*)d_out;

    k_prep_tgt<<<dim3(Mm / 64, Cc / 64, Bb), 256, 0, stream>>>(tgt_desc, tmc, tcm, ps, ps2);
    k_stats<<<dim3(Mm / 256, Bb), 256, 0, stream>>>(ps, ps2, tgt_coords, tgt_weights, scl, tcm);
    k_prep_src<<<dim3(Nn / 64, Cc / 64, Bb), 256, 0, stream>>>(src_desc, snc);
    k_main<<<dim3(MCn, Nn / 128, Bb), 256, 0, stream>>>(tmc, tcm, snc, scl, part, zp, pp);
    (void)hipMemsetAsync((char*)d_out + O_MAXSM * 4, 0, 2 * sizeof(float), stream);
    k_epi<<<dim3((Bb * Nn) / 4), 256, 0, stream>>>(part, zp, pp, out);
}

// Round 11
// 370.398 us; speedup vs baseline: 1.3094x; 1.1559x over previous
//
#include <hip/hip_runtime.h>
#include <hip/hip_bf16.h>

// ---------------- problem constants ----------------
#define Bb   2
#define Cc   256
#define Nn   1024
#define Mm   65536
#define MCn  16           // m-chunks (global partials, bf16)
#define VROWS 272         // 256 desc + 3 coords + 1 weight + ones + 11 pad
#define MSTEP 32
#define MCHUNK (Mm / MCn)           // 4096
#define NIT  (MCHUNK / MSTEP)       // 128 K-steps per block

// workspace byte offsets
#define SCL_OFF  0L                               // B*M f32           (0.5 MB)
#define TMC_OFF  524288L                          // B*M*C bf16        (67 MB)   K: [b][m][c]
#define TCM_OFF  67633152L                        // B*272*M bf16      (71.3 MB) V: [b][row][m]
#define SNC_OFF  138936320L                       // B*N*C bf16        (1 MB)    Q^T: [b][n][c]
#define PART_OFF 139984896L                       // B*16*N*272 bf16   (17.8 MB)
#define ZP_OFF   157810688L                       // B*16*N f32
#define PP_OFF   157941760L                       // B*16*N f32  (end 158072832)
// stats partials live in the part region (used before k_main writes part)
#define PS_OFF   PART_OFF                         // [B][4][M] f32 sums   (2 MB)
#define PS2_OFF  (PART_OFF + 2097152L)            // [B][4][M] f32 sumsq  (2 MB)

// output float offsets
#define O_COORD 0L
#define O_W     6144L
#define O_DESC  8192L
#define O_P2D   532480L
#define O_VALID 536576L
#define O_MAXSM 538624L

using f32x4 = __attribute__((ext_vector_type(4))) float;
using s16x8 = __attribute__((ext_vector_type(8))) short;

__device__ inline unsigned short f2bf(float x) {
    union { float f; unsigned int u; } v; v.f = x;
    unsigned int r = v.u + 0x7FFFu + ((v.u >> 16) & 1u);   // RNE
    return (unsigned short)(r >> 16);
}
__device__ inline float bf2f(unsigned short u) {
    union { unsigned int u; float f; } v; v.u = ((unsigned int)u) << 16;
    return v.f;
}
__device__ inline float exp2v(float x) {
    float r; asm("v_exp_f32 %0, %1" : "=v"(r) : "v"(x)); return r;
}
__device__ inline unsigned int cvtpk(float lo, float hi) {
    unsigned int r;
    asm("v_cvt_pk_bf16_f32 %0, %1, %2" : "=v"(r) : "v"(lo), "v"(hi));
    return r;
}

__device__ inline void gld_lds16(const unsigned short* g, unsigned short* l) {
    __builtin_amdgcn_global_load_lds(
        (const __attribute__((address_space(1))) unsigned int*)g,
        (__attribute__((address_space(3))) unsigned int*)l, 16, 0, 0);
}

// ------- prep A: tgt_desc f32 -> tmc bf16 [b][m][c] + tcm bf16 [b][c][m],
//                 plus per-(c-block, m) partial sums for the column stats -------
__global__ void k_prep_tgt(const float* __restrict__ tgt,
                           unsigned short* __restrict__ tmc,
                           unsigned short* __restrict__ tcm,
                           float* __restrict__ ps,
                           float* __restrict__ ps2) {
    __shared__ float lds[64][65];
    __shared__ float sm[4][64], sm2[4][64];
    int b = blockIdx.z, cy = blockIdx.y, c0 = cy * 64;
    long m0 = (long)blockIdx.x * 64;
    int ty = threadIdx.x >> 6, tx = threadIdx.x & 63;
    float s = 0.f, s2 = 0.f;
    #pragma unroll
    for (int k = 0; k < 16; ++k) {
        int ci = 4 * k + ty;
        float v = tgt[((long)b * Cc + c0 + ci) * Mm + m0 + tx];
        lds[ci][tx] = v;
        s += v; s2 += v * v;
        tcm[((long)b * VROWS + c0 + ci) * Mm + m0 + tx] = f2bf(v);
    }
    sm[ty][tx] = s; sm2[ty][tx] = s2;
    __syncthreads();
    #pragma unroll
    for (int k = 0; k < 16; ++k) {
        int mi = 4 * k + ty;
        tmc[((long)b * Mm + m0 + mi) * Cc + c0 + tx] = f2bf(lds[tx][mi]);
    }
    if (ty == 0) {
        long o = ((long)b * 4 + cy) * Mm + m0 + tx;
        ps[o]  = (sm[0][tx] + sm[1][tx]) + (sm[2][tx] + sm[3][tx]);
        ps2[o] = (sm2[0][tx] + sm2[1][tx]) + (sm2[2][tx] + sm2[3][tx]);
    }
}

// ------- prep B: finish stats -> scl; write coords/weights/ones rows of V -------
__global__ void k_stats(const float* __restrict__ ps,
                        const float* __restrict__ ps2,
                        const float* __restrict__ coords,
                        const float* __restrict__ weights,
                        float* __restrict__ scl,
                        unsigned short* __restrict__ tcm) {
    int b = blockIdx.y;
    long m = (long)blockIdx.x * 256 + threadIdx.x;
    float s = 0.f, s2 = 0.f;
    #pragma unroll
    for (int k = 0; k < 4; ++k) {
        long o = ((long)b * 4 + k) * Mm + m;
        s += ps[o]; s2 += ps2[o];
    }
    float var = fmaxf((s2 - s * s * (1.0f / Cc)) * (1.0f / (Cc - 1)), 1e-20f);
    scl[(long)b * Mm + m] = 1.4426950408889634f * rsqrtf(var) * (1.0f / (Cc * 0.01f));
    unsigned short* vrow = tcm + ((long)b * VROWS + 256) * Mm + m;
    #pragma unroll
    for (int i = 0; i < 3; ++i) vrow[(long)i * Mm] = f2bf(coords[((long)b * 3 + i) * Mm + m]);
    vrow[3L * Mm] = f2bf(weights[(long)b * Mm + m]);
    vrow[4L * Mm] = 0x3F80;   // ones row (channel 260): Z comes out of the PV MFMA
    #pragma unroll
    for (int i = 5; i < 16; ++i) vrow[(long)i * Mm] = 0;
}

// ------- prep C: src_desc_norm f32 -> snc bf16 [b][n][c] -------
__global__ void k_prep_src(const float* __restrict__ src, unsigned short* __restrict__ snc) {
    __shared__ float lds[64][65];
    int b = blockIdx.z, c0 = blockIdx.y * 64, n0 = blockIdx.x * 64;
    int ty = threadIdx.x >> 6, tx = threadIdx.x & 63;
    #pragma unroll
    for (int k = 0; k < 16; ++k)
        lds[4 * k + ty][tx] = src[((long)b * Cc + c0 + 4 * k + ty) * Nn + n0 + tx];
    __syncthreads();
    #pragma unroll
    for (int k = 0; k < 16; ++k) {
        int ni = 4 * k + ty;
        snc[((long)b * Nn + n0 + ni) * Cc + c0 + tx] = f2bf(lds[tx][ni]);
    }
}

// ------- main fused kernel: depth-2 staging, counted-vmcnt raw barriers -------
// 4 waves * 32 n = 128 n; 128 steps of 32 m. K and V in 4-deep rotating LDS
// buffers; stage(s+2) issued each iter; barrier = s_waitcnt vmcnt(8|9) +
// raw s_barrier, so staging loads stay in flight across barriers (T3/T4).
// PV(s-1) software-pipelined one step behind QK(s).
__global__ __launch_bounds__(256, 1) void k_main(const unsigned short* __restrict__ tmc,
                                                 const unsigned short* __restrict__ tcm,
                                                 const unsigned short* __restrict__ snc,
                                                 const float* __restrict__ scl,
                                                 unsigned short* __restrict__ part,
                                                 float* __restrict__ zp,
                                                 float* __restrict__ pp) {
    __shared__ __align__(16) unsigned short kb[4][8192];              // 64 KB
    __shared__ __align__(16) unsigned short vb[4][8704];              // 68 KB
    __shared__ __align__(16) unsigned short pbuf[2][4][2][16][40];    // 20.5 KB

    int w = threadIdx.x >> 6, lane = threadIdx.x & 63;
    int l15 = lane & 15, lg = lane >> 4;
    int b = blockIdx.z, nt = blockIdx.y, mc = blockIdx.x;
    int nb = nt * 128 + w * 32;
    long mbase = (long)mc * MCHUNK;

    // Q^T B-fragments for 2 n-subtiles (permanent registers)
    s16x8 qf[2][8];
    #pragma unroll
    for (int st = 0; st < 2; ++st) {
        const unsigned short* qp = snc + ((long)b * Nn + nb + st * 16 + l15) * Cc + lg * 8;
        #pragma unroll
        for (int cc = 0; cc < 8; ++cc) qf[st][cc] = *(const s16x8*)(qp + cc * 32);
    }

    f32x4 acc[2][17];
    #pragma unroll
    for (int st = 0; st < 2; ++st)
        #pragma unroll
        for (int t = 0; t < 17; ++t) acc[st][t] = (f32x4){0.f, 0.f, 0.f, 0.f};
    float pmax[2] = {0.f, 0.f};

    // ---- staging source pointers (per-lane, pre-swizzled) ----
    const unsigned short* tmcb = tmc + (long)b * Mm * Cc;
    const unsigned short* tcmb = tcm + (long)b * VROWS * (long)Mm;
    const unsigned short* ksrc[4];
    #pragma unroll
    for (int i = 0; i < 4; ++i) {
        int ins = w * 4 + i;                 // K instr 0..15, covers rows 2*ins, 2*ins+1
        int row = 2 * ins + (lane >> 5);
        int gs  = (lane & 31) ^ (row & 7);   // pre-swizzled 16B slot
        ksrc[i] = tmcb + (mbase + row) * Cc + gs * 8;
    }
    const unsigned short* vsrc[5];
    int vj = ((lane & 3) ^ ((lane >> 3) & 3)) * 8;   // chunk-XOR pre-swizzle
    #pragma unroll
    for (int i = 0; i < 5; ++i) {
        int ins = (i < 4) ? (w * 4 + i) : 16;
        int row = ins * 16 + (lane >> 2);
        vsrc[i] = tcmb + (long)row * Mm + mbase + vj;
    }

    const float* sclb = scl + (long)b * Mm;

    auto stage = [&](int d) {
        unsigned short* kd = kb[d];
        unsigned short* vd = vb[d];
        #pragma unroll
        for (int i = 0; i < 4; ++i) gld_lds16(ksrc[i], kd + (w * 4 + i) * 512);
        #pragma unroll
        for (int i = 0; i < 4; ++i) gld_lds16(vsrc[i], vd + (w * 4 + i) * 512);
        if (w == 3) gld_lds16(vsrc[4], vd + 16 * 512);
        #pragma unroll
        for (int i = 0; i < 4; ++i) ksrc[i] += MSTEP * Cc;
        #pragma unroll
        for (int i = 0; i < 5; ++i) vsrc[i] += MSTEP;
    };

    int ksw = (l15 & 7) << 3;              // K read swizzle (elements)
    int vsw = (lg ^ ((l15 >> 1) & 3)) * 8; // V read chunk swizzle (elements)

    // counted-vmcnt barrier: leave this wave's newest staging batch in flight
    auto cbar = [&](bool counted) {
        if (counted) {
            if (w == 3) asm volatile("s_waitcnt vmcnt(9)" ::: "memory");
            else        asm volatile("s_waitcnt vmcnt(8)" ::: "memory");
        } else {
            asm volatile("s_waitcnt vmcnt(0)" ::: "memory");
        }
        __builtin_amdgcn_s_barrier();
        __builtin_amdgcn_sched_barrier(0);
    };

    // prologue: scl(0), tiles 0 and 1 staged; wait for tile 0, keep tile 1 in flight
    float4 scA = *(const float4*)(sclb + mbase + lg * 4);
    float4 scB = *(const float4*)(sclb + mbase + 16 + lg * 4);
    stage(0);
    stage(1);
    cbar(true);

    for (int s = 0; s < NIT; ++s) {
        // scl for s+1 first (older than staging -> drained harmlessly at barrier)
        int sn = (s + 1 < NIT) ? s + 1 : s;
        float4 nA = *(const float4*)(sclb + mbase + (long)sn * MSTEP + lg * 4);
        float4 nB = *(const float4*)(sclb + mbase + (long)sn * MSTEP + 16 + lg * 4);
        bool deep = (s + 2 < NIT);
        if (deep) stage((s + 2) & 3);

        // ---- QK(s) from kb[s&3] -> pbuf[s&1] ----
        const unsigned short* kbc = kb[s & 3];
        unsigned short* pw = &pbuf[s & 1][w][0][0][0];
        #pragma unroll
        for (int t = 0; t < 2; ++t) {
            f32x4 dA = (f32x4){0.f, 0.f, 0.f, 0.f};
            f32x4 dB = (f32x4){0.f, 0.f, 0.f, 0.f};
            const unsigned short* kr = kbc + (t * 16 + l15) * Cc;
            #pragma unroll
            for (int cc = 0; cc < 8; ++cc) {
                s16x8 kf = *(const s16x8*)(kr + ((cc * 32 + lg * 8) ^ ksw));
                dA = __builtin_amdgcn_mfma_f32_16x16x32_bf16(kf, qf[0][cc], dA, 0, 0, 0);
                dB = __builtin_amdgcn_mfma_f32_16x16x32_bf16(kf, qf[1][cc], dB, 0, 0, 0);
            }
            float4 sc = t ? scB : scA;
            #pragma unroll
            for (int st = 0; st < 2; ++st) {
                f32x4 d = st ? dB : dA;
                float p0 = exp2v(d.x * sc.x);
                float p1 = exp2v(d.y * sc.y);
                float p2 = exp2v(d.z * sc.z);
                float p3 = exp2v(d.w * sc.w);
                pmax[st] = fmaxf(pmax[st], fmaxf(fmaxf(p0, p1), fmaxf(p2, p3)));
                unsigned long long pk =
                    (unsigned long long)cvtpk(p0, p1) | ((unsigned long long)cvtpk(p2, p3) << 32);
                *(unsigned long long*)(pw + (st * 16 + l15) * 40 + t * 16 + lg * 4) = pk;
            }
        }

        // ---- PV(s-1) from vb[(s-1)&3], pbuf[(s-1)&1] ----
        if (s) {
            const unsigned short* vbc = vb[(s + 3) & 3];
            const unsigned short* pr = &pbuf[(s & 1) ^ 1][w][0][0][0];
            s16x8 pfA = *(const s16x8*)(pr + l15 * 40 + lg * 8);
            s16x8 pfB = *(const s16x8*)(pr + (16 + l15) * 40 + lg * 8);
            #pragma unroll
            for (int t = 0; t < 17; ++t) {
                s16x8 vf = *(const s16x8*)(vbc + (t * 16 + l15) * MSTEP + vsw);
                acc[0][t] = __builtin_amdgcn_mfma_f32_16x16x32_bf16(vf, pfA, acc[0][t], 0, 0, 0);
                acc[1][t] = __builtin_amdgcn_mfma_f32_16x16x32_bf16(vf, pfB, acc[1][t], 0, 0, 0);
            }
        }

        scA = nA; scB = nB;
        cbar(deep);
    }

    // tail: PV(NIT-1)
    {
        const unsigned short* vbc = vb[(NIT - 1) & 3];
        const unsigned short* pr = &pbuf[(NIT - 1) & 1][w][0][0][0];
        s16x8 pfA = *(const s16x8*)(pr + l15 * 40 + lg * 8);
        s16x8 pfB = *(const s16x8*)(pr + (16 + l15) * 40 + lg * 8);
        #pragma unroll
        for (int t = 0; t < 17; ++t) {
            s16x8 vf = *(const s16x8*)(vbc + (t * 16 + l15) * MSTEP + vsw);
            acc[0][t] = __builtin_amdgcn_mfma_f32_16x16x32_bf16(vf, pfA, acc[0][t], 0, 0, 0);
            acc[1][t] = __builtin_amdgcn_mfma_f32_16x16x32_bf16(vf, pfB, acc[1][t], 0, 0, 0);
        }
    }

    // Z sits in acc[st][16].x on lanes lg==1 (channel 260 = ones row)
    #pragma unroll
    for (int st = 0; st < 2; ++st) {
        float pt = fmaxf(pmax[st], __shfl_xor(pmax[st], 16));
        pt = fmaxf(pt, __shfl_xor(pt, 32));
        long zi = ((long)(b * MCn + mc)) * Nn + nb + st * 16;
        if (lg == 1) zp[zi + l15] = acc[st][16].x;
        if (lane < 16) pp[zi + lane] = pt;
        unsigned short* po = part + (((long)(b * MCn + mc) * Nn) + nb + st * 16 + l15) * VROWS;
        #pragma unroll
        for (int t = 0; t < 17; ++t) {
            f32x4 a = acc[st][t];
            unsigned long long pk =
                (unsigned long long)cvtpk(a.x, a.y) | ((unsigned long long)cvtpk(a.z, a.w) << 32);
            *(unsigned long long*)&po[t * 16 + lg * 4] = pk;
        }
    }
}

// ------- epilogue: combine m-chunks, normalize, zn(descs), 2D projection, max_softmax -------
__global__ void k_epi(const unsigned short* __restrict__ part,
                      const float* __restrict__ zp,
                      const float* __restrict__ pp,
                      float* __restrict__ out) {
    int w = threadIdx.x >> 6, lane = threadIdx.x & 63;
    int bn = blockIdx.x * 4 + w;
    int b = bn >> 10, n = bn & 1023;

    float Z = 0.f, pm = 0.f;
    #pragma unroll
    for (int mc = 0; mc < MCn; ++mc) {
        long zi = ((long)(b * MCn + mc)) * Nn + n;
        Z += zp[zi];
        pm = fmaxf(pm, pp[zi]);
    }
    float invZ = 1.0f / Z;

    float dv[4], s1 = 0.f, s2 = 0.f;
    #pragma unroll
    for (int k = 0; k < 4; ++k) {
        int c = lane + 64 * k;
        float s = 0.f;
        #pragma unroll
        for (int mc = 0; mc < MCn; ++mc)
            s += bf2f(part[((long)(b * MCn + mc) * Nn + n) * VROWS + c]);
        float d = s * invZ;
        dv[k] = d; s1 += d; s2 += d * d;
    }
    #pragma unroll
    for (int off = 1; off < 64; off <<= 1) { s1 += __shfl_xor(s1, off); s2 += __shfl_xor(s2, off); }
    float mean = s1 * (1.0f / 256.0f);
    float var = fmaxf((s2 - 256.0f * mean * mean) * (1.0f / 255.0f), 1e-20f);
    float istd = 1.0f / sqrtf(var);
    #pragma unroll
    for (int k = 0; k < 4; ++k)
        out[O_DESC + ((long)b * Cc + lane + 64 * k) * Nn + n] = (dv[k] - mean) * istd;

    float ex = 0.f;
    if (lane < 4) {
        int c = 256 + lane;
        #pragma unroll
        for (int mc = 0; mc < MCn; ++mc)
            ex += bf2f(part[((long)(b * MCn + mc) * Nn + n) * VROWS + c]);
        ex *= invZ;
    }
    float pc0 = __shfl(ex, 0), pc1 = __shfl(ex, 1), pc2 = __shfl(ex, 2), wv = __shfl(ex, 3);
    if (lane == 0) {
        out[O_COORD + ((long)b * 3 + 0) * Nn + n] = pc0;
        out[O_COORD + ((long)b * 3 + 1) * Nn + n] = pc1;
        out[O_COORD + ((long)b * 3 + 2) * Nn + n] = pc2;
        out[O_W + (long)b * Nn + n] = wv;
        const float cmin = 33.048f;                 // (256/2 - 0.5) * 0.2592
        out[O_P2D + ((long)b * Nn + n) * 2 + 0] = (cmin + pc1) * (1.0f / 0.2592f);
        out[O_P2D + ((long)b * Nn + n) * 2 + 1] = (cmin - pc0) * (1.0f / 0.2592f);
        out[O_VALID + (long)b * Nn + n] = 1.0f;
        atomicMax((unsigned int*)out + O_MAXSM + b, __float_as_uint(pm * invZ));
    }
}

extern "C" void kernel_launch(void* const* d_in, const int* in_sizes, int n_in,
                              void* d_out, int out_size, void* d_ws, size_t ws_size,
                              hipStream_t stream) {
    const float* tgt_coords  = (const float*)d_in[1];
    const float* tgt_weights = (const float*)d_in[3];
    const float* src_desc    = (const float*)d_in[5];
    const float* tgt_desc    = (const float*)d_in[6];

    char* ws = (char*)d_ws;
    float* scl           = (float*)(ws + SCL_OFF);
    unsigned short* tmc  = (unsigned short*)(ws + TMC_OFF);
    unsigned short* tcm  = (unsigned short*)(ws + TCM_OFF);
    unsigned short* snc  = (unsigned short*)(ws + SNC_OFF);
    unsigned short* part = (unsigned short*)(ws + PART_OFF);
    float* ps            = (float*)(ws + PS_OFF);
    float* ps2           = (float*)(ws + PS2_OFF);
    float* zp            = (float*)(ws + ZP_OFF);
    float* pp            = (float*)(ws + PP_OFF);
    float* out           = (float*)d_out;

    k_prep_tgt<<<dim3(Mm / 64, Cc / 64, Bb), 256, 0, stream>>>(tgt_desc, tmc, tcm, ps, ps2);
    k_stats<<<dim3(Mm / 256, Bb), 256, 0, stream>>>(ps, ps2, tgt_coords, tgt_weights, scl, tcm);
    k_prep_src<<<dim3(Nn / 64, Cc / 64, Bb), 256, 0, stream>>>(src_desc, snc);
    k_main<<<dim3(MCn, Nn / 128, Bb), 256, 0, stream>>>(tmc, tcm, snc, scl, part, zp, pp);
    (void)hipMemsetAsync((char*)d_out + O_MAXSM * 4, 0, 2 * sizeof(float), stream);
    k_epi<<<dim3((Bb * Nn) / 4), 256, 0, stream>>>(part, zp, pp, out);
}

// Round 12
// 327.281 us; speedup vs baseline: 1.4819x; 1.1317x over previous
//
#include <hip/hip_runtime.h>
#include <hip/hip_bf16.h>

// ---------------- problem constants ----------------
#define Bb   2
#define Cc   256
#define Nn   1024
#define Mm   65536
#define VROWS 272         // 256 desc + 3 coords + 1 weight + ones + 11 pad
#define MSTEP 32

// workspace byte offsets (fixed part)
#define SCL_OFF  0L                               // B*M f32           (0.5 MB)
#define TMC_OFF  524288L                          // B*M*C bf16        (67 MB)   K: [b][m][c]
#define TCM_OFF  67633152L                        // B*272*M bf16      (71.3 MB) V: [b][row][m]
#define SNC_OFF  138936320L                       // B*N*C bf16        (1 MB)    Q^T: [b][n][c]
#define PART_OFF 139984896L                       // B*MCn*N*272 bf16  (MCn runtime)
// stats partials live in the part region (consumed before k_main writes part)
#define PS_OFF   PART_OFF                         // [B][4][M] f32 sums   (2 MB)
#define PS2_OFF  (PART_OFF + 2097152L)            // [B][4][M] f32 sumsq  (2 MB)

// output float offsets
#define O_COORD 0L
#define O_W     6144L
#define O_DESC  8192L
#define O_P2D   532480L
#define O_VALID 536576L
#define O_MAXSM 538624L

using f32x4 = __attribute__((ext_vector_type(4))) float;
using s16x8 = __attribute__((ext_vector_type(8))) short;

__device__ inline unsigned short f2bf(float x) {
    union { float f; unsigned int u; } v; v.f = x;
    unsigned int r = v.u + 0x7FFFu + ((v.u >> 16) & 1u);   // RNE
    return (unsigned short)(r >> 16);
}
__device__ inline float bf2f(unsigned short u) {
    union { unsigned int u; float f; } v; v.u = ((unsigned int)u) << 16;
    return v.f;
}
__device__ inline float exp2v(float x) {
    float r; asm("v_exp_f32 %0, %1" : "=v"(r) : "v"(x)); return r;
}
__device__ inline unsigned int cvtpk(float lo, float hi) {
    unsigned int r;
    asm("v_cvt_pk_bf16_f32 %0, %1, %2" : "=v"(r) : "v"(lo), "v"(hi));
    return r;
}

__device__ inline void gld_lds16(const unsigned short* g, unsigned short* l) {
    __builtin_amdgcn_global_load_lds(
        (const __attribute__((address_space(1))) unsigned int*)g,
        (__attribute__((address_space(3))) unsigned int*)l, 16, 0, 0);
}

// ------- prep A: tgt_desc f32 -> tmc bf16 [b][m][c] + tcm bf16 [b][c][m],
//                 plus per-(c-block, m) partial sums for the column stats -------
__global__ void k_prep_tgt(const float* __restrict__ tgt,
                           unsigned short* __restrict__ tmc,
                           unsigned short* __restrict__ tcm,
                           float* __restrict__ ps,
                           float* __restrict__ ps2) {
    __shared__ float lds[64][65];
    __shared__ float sm[4][64], sm2[4][64];
    int b = blockIdx.z, cy = blockIdx.y, c0 = cy * 64;
    long m0 = (long)blockIdx.x * 64;
    int ty = threadIdx.x >> 6, tx = threadIdx.x & 63;
    float s = 0.f, s2 = 0.f;
    #pragma unroll
    for (int k = 0; k < 16; ++k) {
        int ci = 4 * k + ty;
        float v = tgt[((long)b * Cc + c0 + ci) * Mm + m0 + tx];
        lds[ci][tx] = v;
        s += v; s2 += v * v;
        tcm[((long)b * VROWS + c0 + ci) * Mm + m0 + tx] = f2bf(v);
    }
    sm[ty][tx] = s; sm2[ty][tx] = s2;
    __syncthreads();
    #pragma unroll
    for (int k = 0; k < 16; ++k) {
        int mi = 4 * k + ty;
        tmc[((long)b * Mm + m0 + mi) * Cc + c0 + tx] = f2bf(lds[tx][mi]);
    }
    if (ty == 0) {
        long o = ((long)b * 4 + cy) * Mm + m0 + tx;
        ps[o]  = (sm[0][tx] + sm[1][tx]) + (sm[2][tx] + sm[3][tx]);
        ps2[o] = (sm2[0][tx] + sm2[1][tx]) + (sm2[2][tx] + sm2[3][tx]);
    }
}

// ------- prep B: finish stats -> scl; write coords/weights/ones rows of V -------
__global__ void k_stats(const float* __restrict__ ps,
                        const float* __restrict__ ps2,
                        const float* __restrict__ coords,
                        const float* __restrict__ weights,
                        float* __restrict__ scl,
                        unsigned short* __restrict__ tcm) {
    int b = blockIdx.y;
    long m = (long)blockIdx.x * 256 + threadIdx.x;
    float s = 0.f, s2 = 0.f;
    #pragma unroll
    for (int k = 0; k < 4; ++k) {
        long o = ((long)b * 4 + k) * Mm + m;
        s += ps[o]; s2 += ps2[o];
    }
    float var = fmaxf((s2 - s * s * (1.0f / Cc)) * (1.0f / (Cc - 1)), 1e-20f);
    scl[(long)b * Mm + m] = 1.4426950408889634f * rsqrtf(var) * (1.0f / (Cc * 0.01f));
    unsigned short* vrow = tcm + ((long)b * VROWS + 256) * Mm + m;
    #pragma unroll
    for (int i = 0; i < 3; ++i) vrow[(long)i * Mm] = f2bf(coords[((long)b * 3 + i) * Mm + m]);
    vrow[3L * Mm] = f2bf(weights[(long)b * Mm + m]);
    vrow[4L * Mm] = 0x3F80;   // ones row (channel 260): Z comes out of the PV MFMA
    #pragma unroll
    for (int i = 5; i < 16; ++i) vrow[(long)i * Mm] = 0;
}

// ------- prep C: src_desc_norm f32 -> snc bf16 [b][n][c] -------
__global__ void k_prep_src(const float* __restrict__ src, unsigned short* __restrict__ snc) {
    __shared__ float lds[64][65];
    int b = blockIdx.z, c0 = blockIdx.y * 64, n0 = blockIdx.x * 64;
    int ty = threadIdx.x >> 6, tx = threadIdx.x & 63;
    #pragma unroll
    for (int k = 0; k < 16; ++k)
        lds[4 * k + ty][tx] = src[((long)b * Cc + c0 + 4 * k + ty) * Nn + n0 + tx];
    __syncthreads();
    #pragma unroll
    for (int k = 0; k < 16; ++k) {
        int ni = 4 * k + ty;
        snc[((long)b * Nn + n0 + ni) * Cc + c0 + tx] = f2bf(lds[tx][ni]);
    }
}

// ------- main fused kernel: 64 n per wave (4 subtiles) -------
// 4 waves * 64 n = 256 n per block; m-chunk = Mm/mcn, nit steps of 32 m.
// Each K-frag and V-frag feeds 4 MFMAs (one per n-subtile): LDS reads per
// MFMA are halved vs 32n/wave. K/V double-buffered; pbuf wave-private.
__global__ __launch_bounds__(256, 1) void k_main(const unsigned short* __restrict__ tmc,
                                                 const unsigned short* __restrict__ tcm,
                                                 const unsigned short* __restrict__ snc,
                                                 const float* __restrict__ scl,
                                                 unsigned short* __restrict__ part,
                                                 float* __restrict__ zp,
                                                 float* __restrict__ pp,
                                                 int mcn) {
    __shared__ __align__(16) unsigned short kb[2][8192];          // 32 KB
    __shared__ __align__(16) unsigned short vb[2][8704];          // 34 KB
    __shared__ __align__(16) unsigned short pbuf[4][4][16][40];   // 20.5 KB

    int w = threadIdx.x >> 6, lane = threadIdx.x & 63;
    int l15 = lane & 15, lg = lane >> 4;
    int b = blockIdx.z, nt = blockIdx.y, mc = blockIdx.x;
    int nb = nt * 256 + w * 64;
    int mchunk = Mm / mcn;
    int nit = mchunk / MSTEP;
    long mbase = (long)mc * mchunk;

    // Q^T B-fragments for 4 n-subtiles (permanent registers, 128 VGPR)
    s16x8 qf[4][8];
    #pragma unroll
    for (int st = 0; st < 4; ++st) {
        const unsigned short* qp = snc + ((long)b * Nn + nb + st * 16 + l15) * Cc + lg * 8;
        #pragma unroll
        for (int cc = 0; cc < 8; ++cc) qf[st][cc] = *(const s16x8*)(qp + cc * 32);
    }

    f32x4 acc[4][17];
    #pragma unroll
    for (int st = 0; st < 4; ++st)
        #pragma unroll
        for (int t = 0; t < 17; ++t) acc[st][t] = (f32x4){0.f, 0.f, 0.f, 0.f};
    float pmax[4] = {0.f, 0.f, 0.f, 0.f};

    // ---- staging source pointers (per-lane, pre-swizzled) ----
    const unsigned short* tmcb = tmc + (long)b * Mm * Cc;
    const unsigned short* tcmb = tcm + (long)b * VROWS * (long)Mm;
    const unsigned short* ksrc[4];
    #pragma unroll
    for (int i = 0; i < 4; ++i) {
        int ins = w * 4 + i;                 // K instr 0..15, covers rows 2*ins, 2*ins+1
        int row = 2 * ins + (lane >> 5);
        int gs  = (lane & 31) ^ (row & 7);   // pre-swizzled 16B slot
        ksrc[i] = tmcb + (mbase + row) * Cc + gs * 8;
    }
    const unsigned short* vsrc[5];
    int vj = ((lane & 3) ^ ((lane >> 3) & 3)) * 8;   // chunk-XOR pre-swizzle
    #pragma unroll
    for (int i = 0; i < 5; ++i) {
        int ins = (i < 4) ? (w * 4 + i) : 16;
        int row = ins * 16 + (lane >> 2);
        vsrc[i] = tcmb + (long)row * Mm + mbase + vj;
    }

    const float* sclb = scl + (long)b * Mm;

    auto stage = [&](int d) {
        unsigned short* kd = kb[d];
        unsigned short* vd = vb[d];
        #pragma unroll
        for (int i = 0; i < 4; ++i) gld_lds16(ksrc[i], kd + (w * 4 + i) * 512);
        #pragma unroll
        for (int i = 0; i < 4; ++i) gld_lds16(vsrc[i], vd + (w * 4 + i) * 512);
        if (w == 3) gld_lds16(vsrc[4], vd + 16 * 512);
        #pragma unroll
        for (int i = 0; i < 4; ++i) ksrc[i] += MSTEP * Cc;
        #pragma unroll
        for (int i = 0; i < 5; ++i) vsrc[i] += MSTEP;
    };

    int ksw = (l15 & 7) << 3;              // K read swizzle (elements)
    int vsw = (lg ^ ((l15 >> 1) & 3)) * 8; // V read chunk swizzle (elements)

    stage(0);
    __syncthreads();

    for (int s = 0; s < nit; ++s) {
        int cur = s & 1;
        if (s + 1 < nit) stage(cur ^ 1);
        const unsigned short* kbc = kb[cur];
        const unsigned short* vbc = vb[cur];
        long m0 = mbase + (long)s * MSTEP;
        float4 sc0 = *(const float4*)(sclb + m0 + lg * 4);
        float4 sc1 = *(const float4*)(sclb + m0 + 16 + lg * 4);

        // ---- QK: 2 m-subtiles x 4 n-subtiles; each kf feeds 4 MFMAs ----
        #pragma unroll
        for (int t = 0; t < 2; ++t) {
            f32x4 dA = (f32x4){0.f, 0.f, 0.f, 0.f};
            f32x4 dB = (f32x4){0.f, 0.f, 0.f, 0.f};
            f32x4 dC = (f32x4){0.f, 0.f, 0.f, 0.f};
            f32x4 dD = (f32x4){0.f, 0.f, 0.f, 0.f};
            const unsigned short* kr = kbc + (t * 16 + l15) * Cc;
            #pragma unroll
            for (int cc = 0; cc < 8; ++cc) {
                s16x8 kf = *(const s16x8*)(kr + ((cc * 32 + lg * 8) ^ ksw));
                dA = __builtin_amdgcn_mfma_f32_16x16x32_bf16(kf, qf[0][cc], dA, 0, 0, 0);
                dB = __builtin_amdgcn_mfma_f32_16x16x32_bf16(kf, qf[1][cc], dB, 0, 0, 0);
                dC = __builtin_amdgcn_mfma_f32_16x16x32_bf16(kf, qf[2][cc], dC, 0, 0, 0);
                dD = __builtin_amdgcn_mfma_f32_16x16x32_bf16(kf, qf[3][cc], dD, 0, 0, 0);
            }
            float4 sc = t ? sc1 : sc0;
            #pragma unroll
            for (int st = 0; st < 4; ++st) {
                f32x4 d = (st == 0) ? dA : (st == 1) ? dB : (st == 2) ? dC : dD;
                float p0 = exp2v(d.x * sc.x);
                float p1 = exp2v(d.y * sc.y);
                float p2 = exp2v(d.z * sc.z);
                float p3 = exp2v(d.w * sc.w);
                pmax[st] = fmaxf(pmax[st], fmaxf(fmaxf(p0, p1), fmaxf(p2, p3)));
                unsigned long long pk =
                    (unsigned long long)cvtpk(p0, p1) | ((unsigned long long)cvtpk(p2, p3) << 32);
                *(unsigned long long*)&pbuf[w][st][l15][t * 16 + lg * 4] = pk;
            }
        }
        // ---- PV: each vf feeds 4 MFMAs (wave-private pbuf, lgkm-ordered) ----
        s16x8 pfA = *(const s16x8*)&pbuf[w][0][l15][lg * 8];
        s16x8 pfB = *(const s16x8*)&pbuf[w][1][l15][lg * 8];
        s16x8 pfC = *(const s16x8*)&pbuf[w][2][l15][lg * 8];
        s16x8 pfD = *(const s16x8*)&pbuf[w][3][l15][lg * 8];
        #pragma unroll
        for (int t = 0; t < 17; ++t) {
            s16x8 vf = *(const s16x8*)(vbc + (t * 16 + l15) * MSTEP + vsw);
            acc[0][t] = __builtin_amdgcn_mfma_f32_16x16x32_bf16(vf, pfA, acc[0][t], 0, 0, 0);
            acc[1][t] = __builtin_amdgcn_mfma_f32_16x16x32_bf16(vf, pfB, acc[1][t], 0, 0, 0);
            acc[2][t] = __builtin_amdgcn_mfma_f32_16x16x32_bf16(vf, pfC, acc[2][t], 0, 0, 0);
            acc[3][t] = __builtin_amdgcn_mfma_f32_16x16x32_bf16(vf, pfD, acc[3][t], 0, 0, 0);
        }
        __syncthreads();
    }

    // Z sits in acc[st][16].x on lanes lg==1 (channel 260 = ones row)
    #pragma unroll
    for (int st = 0; st < 4; ++st) {
        float pt = fmaxf(pmax[st], __shfl_xor(pmax[st], 16));
        pt = fmaxf(pt, __shfl_xor(pt, 32));
        long zi = ((long)(b * mcn + mc)) * Nn + nb + st * 16;
        if (lg == 1) zp[zi + l15] = acc[st][16].x;
        if (lane < 16) pp[zi + lane] = pt;
        unsigned short* po = part + (((long)(b * mcn + mc) * Nn) + nb + st * 16 + l15) * VROWS;
        #pragma unroll
        for (int t = 0; t < 17; ++t) {
            f32x4 a = acc[st][t];
            unsigned long long pk =
                (unsigned long long)cvtpk(a.x, a.y) | ((unsigned long long)cvtpk(a.z, a.w) << 32);
            *(unsigned long long*)&po[t * 16 + lg * 4] = pk;
        }
    }
}

// ------- epilogue: combine m-chunks, normalize, zn(descs), 2D projection, max_softmax -------
__global__ void k_epi(const unsigned short* __restrict__ part,
                      const float* __restrict__ zp,
                      const float* __restrict__ pp,
                      float* __restrict__ out,
                      int mcn) {
    int w = threadIdx.x >> 6, lane = threadIdx.x & 63;
    int bn = blockIdx.x * 4 + w;
    int b = bn >> 10, n = bn & 1023;

    float Z = 0.f, pm = 0.f;
    for (int mc = 0; mc < mcn; ++mc) {
        long zi = ((long)(b * mcn + mc)) * Nn + n;
        Z += zp[zi];
        pm = fmaxf(pm, pp[zi]);
    }
    float invZ = 1.0f / Z;

    float dv[4], s1 = 0.f, s2 = 0.f;
    #pragma unroll
    for (int k = 0; k < 4; ++k) {
        int c = lane + 64 * k;
        float s = 0.f;
        for (int mc = 0; mc < mcn; ++mc)
            s += bf2f(part[((long)(b * mcn + mc) * Nn + n) * VROWS + c]);
        float d = s * invZ;
        dv[k] = d; s1 += d; s2 += d * d;
    }
    #pragma unroll
    for (int off = 1; off < 64; off <<= 1) { s1 += __shfl_xor(s1, off); s2 += __shfl_xor(s2, off); }
    float mean = s1 * (1.0f / 256.0f);
    float var = fmaxf((s2 - 256.0f * mean * mean) * (1.0f / 255.0f), 1e-20f);
    float istd = 1.0f / sqrtf(var);
    #pragma unroll
    for (int k = 0; k < 4; ++k)
        out[O_DESC + ((long)b * Cc + lane + 64 * k) * Nn + n] = (dv[k] - mean) * istd;

    float ex = 0.f;
    if (lane < 4) {
        int c = 256 + lane;
        for (int mc = 0; mc < mcn; ++mc)
            ex += bf2f(part[((long)(b * mcn + mc) * Nn + n) * VROWS + c]);
        ex *= invZ;
    }
    float pc0 = __shfl(ex, 0), pc1 = __shfl(ex, 1), pc2 = __shfl(ex, 2), wv = __shfl(ex, 3);
    if (lane == 0) {
        out[O_COORD + ((long)b * 3 + 0) * Nn + n] = pc0;
        out[O_COORD + ((long)b * 3 + 1) * Nn + n] = pc1;
        out[O_COORD + ((long)b * 3 + 2) * Nn + n] = pc2;
        out[O_W + (long)b * Nn + n] = wv;
        const float cmin = 33.048f;                 // (256/2 - 0.5) * 0.2592
        out[O_P2D + ((long)b * Nn + n) * 2 + 0] = (cmin + pc1) * (1.0f / 0.2592f);
        out[O_P2D + ((long)b * Nn + n) * 2 + 1] = (cmin - pc0) * (1.0f / 0.2592f);
        out[O_VALID + (long)b * Nn + n] = 1.0f;
        atomicMax((unsigned int*)out + O_MAXSM + b, __float_as_uint(pm * invZ));
    }
}

extern "C" void kernel_launch(void* const* d_in, const int* in_sizes, int n_in,
                              void* d_out, int out_size, void* d_ws, size_t ws_size,
                              hipStream_t stream) {
    const float* tgt_coords  = (const float*)d_in[1];
    const float* tgt_weights = (const float*)d_in[3];
    const float* src_desc    = (const float*)d_in[5];
    const float* tgt_desc    = (const float*)d_in[6];

    char* ws = (char*)d_ws;
    float* scl           = (float*)(ws + SCL_OFF);
    unsigned short* tmc  = (unsigned short*)(ws + TMC_OFF);
    unsigned short* tcm  = (unsigned short*)(ws + TCM_OFF);
    unsigned short* snc  = (unsigned short*)(ws + SNC_OFF);
    unsigned short* part = (unsigned short*)(ws + PART_OFF);
    float* ps            = (float*)(ws + PS_OFF);
    float* ps2           = (float*)(ws + PS2_OFF);
    float* out           = (float*)d_out;

    // choose m-chunk count by available workspace: 32 chunks needs ~176 MB
    long need32 = PART_OFF + (long)Bb * 32 * Nn * VROWS * 2 + 2L * Bb * 32 * Nn * 4;
    int mcn = (ws_size >= (size_t)need32) ? 32 : 16;
    long zp_off = PART_OFF + (long)Bb * mcn * Nn * VROWS * 2;
    long pp_off = zp_off + (long)Bb * mcn * Nn * 4;
    float* zp = (float*)(ws + zp_off);
    float* pp = (float*)(ws + pp_off);

    k_prep_tgt<<<dim3(Mm / 64, Cc / 64, Bb), 256, 0, stream>>>(tgt_desc, tmc, tcm, ps, ps2);
    k_stats<<<dim3(Mm / 256, Bb), 256, 0, stream>>>(ps, ps2, tgt_coords, tgt_weights, scl, tcm);
    k_prep_src<<<dim3(Nn / 64, Cc / 64, Bb), 256, 0, stream>>>(src_desc, snc);
    k_main<<<dim3(mcn, Nn / 256, Bb), 256, 0, stream>>>(tmc, tcm, snc, scl, part, zp, pp, mcn);
    (void)hipMemsetAsync((char*)d_out + O_MAXSM * 4, 0, 2 * sizeof(float), stream);
    k_epi<<<dim3((Bb * Nn) / 4), 256, 0, stream>>>(part, zp, pp, out, mcn);
}